// Round 18
// baseline (595.962 us; speedup 1.0000x reference)
//
#include <hip/hip_runtime.h>

static constexpr int NN = 100000;   // nodes
static constexpr int NE = 1600000;  // edges
static constexpr int NB = 256;     // graphs
static constexpr int NO = 32;      // orders per graph
static constexpr int HD = 128;     // hidden dim
static constexpr long NH = (long)NN * HD;

static constexpr int BSHIFT = 9;                 // bucket = dst >> 9
static constexpr int BSIZE = 1 << BSHIFT;        // 512 nodes per bucket
static constexpr int NBUCK = 256;
static constexpr int BCAP = 10240;               // fixed bucket capacity (max count ~8650)
static constexpr int CHUNK = 16384;
static constexpr int NCHUNK = (NE + CHUNK - 1) / CHUNK;  // 98
static constexpr int POOL_ROWS = 64;
static constexpr int POOL_GRID = (NN + POOL_ROWS - 1) / POOL_ROWS;  // 1563
static constexpr int NSUB = 64;                  // BN stat sub-accumulators
static constexpr int GATHER_GRID = NN / 4;       // 25000
static constexpr int FL_TILES = (NN + 31) / 32;  // 3125 tiles of 32 rows
static constexpr int FL_GRID = (FL_TILES + 1) / 2;  // 1563 blocks, 2 tiles each

typedef _Float16 f16x8 __attribute__((ext_vector_type(8)));
typedef _Float16 f16x4 __attribute__((ext_vector_type(4)));
typedef _Float16 f16x2 __attribute__((ext_vector_type(2)));
typedef float f32x4 __attribute__((ext_vector_type(4)));

__device__ __forceinline__ unsigned int encf(float f) {
  unsigned int u = __float_as_uint(f);
  return (u & 0x80000000u) ? ~u : (u | 0x80000000u);
}
__device__ __forceinline__ float decf(unsigned int e) {
  return (e & 0x80000000u) ? __uint_as_float(e & 0x7fffffffu) : __uint_as_float(~e);
}

// ================= CSR build (2 kernels): cursor-allocated fixed bucket regions =================
__global__ void bucket_scatter(const int* __restrict__ ei, int* __restrict__ cursor,
                               unsigned int* __restrict__ binned) {
  __shared__ int cnt[NBUCK];
  __shared__ int runbase[NBUCK];
  const int t = threadIdx.x;  // 256
  cnt[t] = 0;
  __syncthreads();
  long start = (long)blockIdx.x * CHUNK;
  long end = min((long)NE, start + CHUNK);
  for (long e = start + t; e < end; e += 256)
    atomicAdd(&cnt[ei[NE + e] >> BSHIFT], 1);
  __syncthreads();
  int c = cnt[t];
  runbase[t] = c ? atomicAdd(&cursor[t], c) : 0;
  cnt[t] = 0;  // reuse as local run cursor
  __syncthreads();
  for (long e = start + t; e < end; e += 256) {
    int d = ei[NE + e], s = ei[e];
    int b = d >> BSHIFT;
    int pos = b * BCAP + runbase[b] + atomicAdd(&cnt[b], 1);
    binned[pos] = ((unsigned int)s << BSHIFT) | (unsigned int)(d & (BSIZE - 1));
  }
}

// per-bucket fine counting sort -> rowStart/rowEnd + col (fixed-region layout)
__global__ void bucket_csr(const unsigned int* __restrict__ binned,
                           const int* __restrict__ cursor,
                           int* __restrict__ rowStart, int* __restrict__ rowEnd,
                           int* __restrict__ col) {
  __shared__ int cnt[BSIZE];
  __shared__ int excl[BSIZE];
  __shared__ int cur[BSIZE];
  __shared__ int part[256];
  const int b = blockIdx.x;
  const int t = threadIdx.x;  // 256
  const int lo = b * BCAP;
  const int hi = lo + cursor[b];
  cnt[t] = 0; cnt[t + 256] = 0;
  __syncthreads();
  for (int i = lo + t; i < hi; i += 256)
    atomicAdd(&cnt[binned[i] & (BSIZE - 1)], 1);
  __syncthreads();
  int a0 = cnt[2 * t], a1 = cnt[2 * t + 1];
  int s = a0 + a1;
  part[t] = s;
  __syncthreads();
  for (int off = 1; off < 256; off <<= 1) {
    int u = (t >= off) ? part[t - off] : 0;
    __syncthreads();
    part[t] += u;
    __syncthreads();
  }
  int ebase = part[t] - s;
  excl[2 * t] = ebase;
  excl[2 * t + 1] = ebase + a0;
  __syncthreads();
  const int node0 = b * BSIZE;
  for (int i = t; i < BSIZE; i += 256) {
    int node = node0 + i;
    if (node < NN) {
      rowStart[node] = lo + excl[i];
      rowEnd[node]   = lo + excl[i] + cnt[i];
    }
    cur[i] = lo + excl[i];
  }
  __syncthreads();
  for (int i = lo + t; i < hi; i += 256) {
    unsigned int v = binned[i];
    int pos = atomicAdd(&cur[v & (BSIZE - 1)], 1);
    col[pos] = (int)(v >> BSHIFT);
  }
}

// ---------------- x fp32 -> fp16, once ----------------
__global__ void f32to16_kernel(const float* __restrict__ in, _Float16* __restrict__ out) {
  long i = (long)(blockIdx.x * 256 + threadIdx.x) * 8;
  if (i >= NH) return;
  float4 a = *reinterpret_cast<const float4*>(in + i);
  float4 b = *reinterpret_cast<const float4*>(in + i + 4);
  f16x8 v;
  v[0] = (_Float16)a.x; v[1] = (_Float16)a.y; v[2] = (_Float16)a.z; v[3] = (_Float16)a.w;
  v[4] = (_Float16)b.x; v[5] = (_Float16)b.y; v[6] = (_Float16)b.z; v[7] = (_Float16)b.w;
  *reinterpret_cast<f16x8*>(out + i) = v;
}

// ---------------- weight packing: fp32 W[128][128] -> fp16 MFMA B-fragments (GIN) ----------------
__global__ void pack_w_kernel(const float* __restrict__ gW1, const float* __restrict__ gW2,
                              _Float16* __restrict__ Wp) {
  int tid = blockIdx.x * blockDim.x + threadIdx.x;  // 3*2*8*4*64 = 12288
  if (tid >= 12288) return;
  int lane = tid & 63;
  int s = (tid >> 6) & 3;
  int t = (tid >> 8) & 7;
  int which = (tid >> 11) & 1;
  int layer = tid >> 12;
  const float* W = (which ? gW2 : gW1) + (long)layer * 128 * 128;
  _Float16* dst = Wp + (long)tid * 8;
  int kbase = s * 32 + ((lane >> 4) << 3);
  int n = t * 16 + (lane & 15);
#pragma unroll
  for (int j = 0; j < 8; ++j) dst[j] = (_Float16)W[(kbase + j) * 128 + n];
}

// ---------------- head weight packing ----------------
__global__ void pack_head_kernel(const float* __restrict__ oW1, const float* __restrict__ oW2,
                                 const float* __restrict__ sW1, const float* __restrict__ sW2,
                                 _Float16* __restrict__ dst) {
  int tid = blockIdx.x * blockDim.x + threadIdx.x;  // 5632 total
  if (tid >= 5632) return;
  const float* W; int K, N, rowOff;
  int base = tid;
  if (tid < 512)       { W = oW1; K = 32;  N = 128; rowOff = 0;   }
  else if (tid < 2560) { W = oW2; K = 128; N = 128; rowOff = 0;   base = tid - 512; }
  else if (tid < 4608) { W = sW1; K = 128; N = 128; rowOff = 384; base = tid - 2560; }
  else                 { W = sW2; K = 128; N = 64;  rowOff = 0;   base = tid - 4608; }
  int lane = base & 63;
  int fs = base >> 6;
  int NS = K >> 5;
  int s = fs % NS;
  int tt = fs / NS;
  int k = s * 32 + ((lane >> 4) << 3);
  int n = tt * 16 + (lane & 15);
  _Float16* d = dst + (long)tid * 8;
#pragma unroll
  for (int j = 0; j < 8; ++j) d[j] = (_Float16)W[(long)(rowOff + k + j) * N + n];
}

// ---------------- gather: z[n] = hn[n] + sum_j hn[col[j]]  (hn pre-normalized) ----------------
__global__ void gather_kernel(const _Float16* __restrict__ hin, const int* __restrict__ rowStart,
                              const int* __restrict__ rowEnd, const int* __restrict__ col,
                              _Float16* __restrict__ z) {
  const int node = (blockIdx.x * blockDim.x + threadIdx.x) >> 6;
  if (node >= NN) return;
  const int c2 = (threadIdx.x & 63) * 2;
  auto ldh = [&](int n) -> float2 {
    f16x2 h = *reinterpret_cast<const f16x2*>(hin + (long)n * HD + c2);
    return make_float2((float)h[0], (float)h[1]);
  };
  const int lo = rowStart[node];
  const int hi = rowEnd[node];
  float2 acc = ldh(node);
  int j = lo;
  for (; j + 4 <= hi; j += 4) {
    int s0 = col[j], s1 = col[j + 1], s2 = col[j + 2], s3 = col[j + 3];
    float2 v0 = ldh(s0), v1 = ldh(s1), v2 = ldh(s2), v3 = ldh(s3);
    acc.x += (v0.x + v1.x) + (v2.x + v3.x);
    acc.y += (v0.y + v1.y) + (v2.y + v3.y);
  }
  if (j < hi) {
    int last = hi - 1;
    int s0 = col[j];
    int s1 = col[min(j + 1, last)];
    int s2 = col[min(j + 2, last)];
    int s3 = col[min(j + 3, last)];
    float m1 = (j + 1 < hi) ? 1.f : 0.f;
    float m2 = (j + 2 < hi) ? 1.f : 0.f;
    float m3 = (j + 3 < hi) ? 1.f : 0.f;
    float2 v0 = ldh(s0), v1 = ldh(s1), v2 = ldh(s2), v3 = ldh(s3);
    acc.x += v0.x + m1 * v1.x + m2 * v2.x + m3 * v3.x;
    acc.y += v0.y + m1 * v1.y + m2 * v2.y + m3 * v3.y;
  }
  f16x2 o;
  o[0] = (_Float16)acc.x;
  o[1] = (_Float16)acc.y;
  *reinterpret_cast<f16x2*>(z + (long)node * HD + c2) = o;
}

// ---------------- fused GIN MLP: 128 threads, 2 pipelined 32-row tiles per block ----------------
// T14 async-stage split: tile1's global loads are ISSUED before tile0's compute; the
// compiler's waitcnt lands at tile1's LDS write (after tile0 compute) so HBM latency
// hides under ~64 MFMA + LDS round-trips. Per tile: wave w owns rows [w*16,w*16+16);
// hidden and z2 round-trip through the wave's own dead LDS rows (DS wave-ordered).
__global__ void __launch_bounds__(128)
fused_layer(const _Float16* __restrict__ Z, const _Float16* __restrict__ Wp,
            const float* __restrict__ b1, const float* __restrict__ b2,
            _Float16* __restrict__ Z2, float* __restrict__ accum2) {
  __shared__ _Float16 A0[32 * 136];
  __shared__ _Float16 A1[32 * 136];
  __shared__ float red[256];
  const int t = threadIdx.x;
  const int lane = t & 63;
  const int w = t >> 6;            // 0..1
  const int l15 = lane & 15;
  const int kgrp = lane >> 4;
  const int row0 = (blockIdx.x * 2) * 32;
  const int row1 = row0 + 32;
  const _Float16* W1p = Wp;
  const _Float16* W2p = Wp + 16384;

  // thread's 4 staging chunks: idx = t + k*128 -> (row r = idx>>4, col c8 = (idx&15)*8)
  // ---- stage tile0 into A0 ----
#pragma unroll
  for (int k = 0; k < 4; ++k) {
    int idx = t + k * 128;
    int r = idx >> 4;
    int c8 = (idx & 15) * 8;
    int row = row0 + r;
    f16x8 v = {};
    if (row < NN) v = *reinterpret_cast<const f16x8*>(Z + (long)row * HD + c8);
    *reinterpret_cast<f16x8*>(&A0[r * 136 + c8]) = v;
  }
  red[t] = 0.f;
  red[t + 128] = 0.f;
  __syncthreads();

  // ---- issue tile1 prefetch (regs); waitcnt will land at the A1 write below ----
  f16x8 p[4];
#pragma unroll
  for (int k = 0; k < 4; ++k) {
    int idx = t + k * 128;
    int r = idx >> 4;
    int c8 = (idx & 15) * 8;
    int row = row1 + r;
    p[k] = (f16x8){};
    if (row < NN) p[k] = *reinterpret_cast<const f16x8*>(Z + (long)row * HD + c8);
  }

  f32x4 acc[8];
  // ================= compute a tile from LDS buffer A (macro-style lambda) =================
  auto compute_tile = [&](_Float16* A, int rowb) {
    // GEMM1: hidden = ReLU(A @ W1 + b1)
    {
      f16x8 af[4];
#pragma unroll
      for (int s = 0; s < 4; ++s)
        af[s] = *reinterpret_cast<const f16x8*>(&A[(w * 16 + l15) * 136 + s * 32 + kgrp * 8]);
#pragma unroll
      for (int tt = 0; tt < 8; ++tt) {
        float bb = b1[tt * 16 + l15];
        acc[tt] = (f32x4){bb, bb, bb, bb};
#pragma unroll
        for (int s = 0; s < 4; ++s) {
          f16x8 bf = *reinterpret_cast<const f16x8*>(W1p + ((tt * 4 + s) * 64 + lane) * 8);
          acc[tt] = __builtin_amdgcn_mfma_f32_16x16x32_f16(af[s], bf, acc[tt], 0, 0, 0);
        }
      }
    }
    // hidden -> wave's own dead rows (DS wave-ordered, no barrier)
#pragma unroll
    for (int tt = 0; tt < 8; ++tt) {
#pragma unroll
      for (int j = 0; j < 4; ++j) {
        float v = fmaxf(acc[tt][j], 0.f);
        A[(w * 16 + kgrp * 4 + j) * 136 + tt * 16 + l15] = (_Float16)v;
      }
    }
    // GEMM2: z2 = hidden @ W2 + b2
    {
      f16x8 af[4];
#pragma unroll
      for (int s = 0; s < 4; ++s)
        af[s] = *reinterpret_cast<const f16x8*>(&A[(w * 16 + l15) * 136 + s * 32 + kgrp * 8]);
#pragma unroll
      for (int tt = 0; tt < 8; ++tt) {
        float bb = b2[tt * 16 + l15];
        acc[tt] = (f32x4){bb, bb, bb, bb};
#pragma unroll
        for (int s = 0; s < 4; ++s) {
          f16x8 bf = *reinterpret_cast<const f16x8*>(W2p + ((tt * 4 + s) * 64 + lane) * 8);
          acc[tt] = __builtin_amdgcn_mfma_f32_16x16x32_f16(af[s], bf, acc[tt], 0, 0, 0);
        }
      }
    }
    // epilogue: stats from regs; z2 -> wave rows -> coalesced store
#pragma unroll
    for (int tt = 0; tt < 8; ++tt) {
      int c = tt * 16 + l15;
      float s = 0.f, q = 0.f;
#pragma unroll
      for (int j = 0; j < 4; ++j) {
        int r = rowb + w * 16 + kgrp * 4 + j;
        float v = acc[tt][j];
        if (r < NN) { s += v; q += v * v; }
        A[(w * 16 + kgrp * 4 + j) * 136 + c] = (_Float16)v;
      }
      atomicAdd(&red[c], s);
      atomicAdd(&red[128 + c], q);
    }
    for (int idx = lane; idx < 16 * 16; idx += 64) {
      int r = w * 16 + (idx >> 4);
      int c8 = (idx & 15) * 8;
      int row = rowb + r;
      if (row < NN)
        *reinterpret_cast<f16x8*>(Z2 + (long)row * HD + c8) =
            *reinterpret_cast<const f16x8*>(&A[r * 136 + c8]);
    }
  };

  // ---- tile0 compute (tile1 loads in flight) ----
  compute_tile(A0, row0);
  __syncthreads();
  // ---- land tile1 into A1 ----
#pragma unroll
  for (int k = 0; k < 4; ++k) {
    int idx = t + k * 128;
    int r = idx >> 4;
    int c8 = (idx & 15) * 8;
    *reinterpret_cast<f16x8*>(&A1[r * 136 + c8]) = p[k];
  }
  __syncthreads();
  // ---- tile1 compute ----
  compute_tile(A1, row1);
  __syncthreads();
  atomicAdd(&accum2[(blockIdx.x & (NSUB - 1)) * 256 + t], red[t]);
  atomicAdd(&accum2[(blockIdx.x & (NSUB - 1)) * 256 + t + 128], red[t + 128]);
}

// ---------------- reduce sub-accumulators -> scsh (scale|shift); self-zero accum2 ----------------
__global__ void bn_reduce(float* __restrict__ accum2, const float* __restrict__ gamma,
                          const float* __restrict__ beta, float* __restrict__ scsh) {
  const int c = threadIdx.x;  // 256
  float s = 0.f;
  for (int i = 0; i < NSUB; ++i) {
    s += accum2[i * 256 + c];
    accum2[i * 256 + c] = 0.f;  // ready for next layer
  }
  __shared__ float red[256];
  red[c] = s;
  __syncthreads();
  if (c < 128) {
    const float n = (float)NN;
    float mu = red[c] / n;
    float var = red[128 + c] / n - mu * mu;
    float sc = rsqrtf(var + 1e-5f) * gamma[c];
    scsh[c] = sc;
    scsh[128 + c] = beta[c] - mu * sc;
  }
}

// ---------------- hn = ReLU(BN(z2)), elementwise ----------------
__global__ void bn_apply(const _Float16* __restrict__ z2, const float* __restrict__ scsh,
                         _Float16* __restrict__ hn) {
  long idx = (long)blockIdx.x * 256 + threadIdx.x;  // NN*16
  if (idx >= (long)NN * 16) return;
  int c8 = ((int)idx & 15) * 8;
  float4 sc0 = *reinterpret_cast<const float4*>(scsh + c8);
  float4 sc1 = *reinterpret_cast<const float4*>(scsh + c8 + 4);
  float4 sh0 = *reinterpret_cast<const float4*>(scsh + 128 + c8);
  float4 sh1 = *reinterpret_cast<const float4*>(scsh + 128 + c8 + 4);
  f16x8 v = *reinterpret_cast<const f16x8*>(z2 + idx * 8);
  f16x8 o;
  o[0] = (_Float16)fmaxf(fmaf((float)v[0], sc0.x, sh0.x), 0.f);
  o[1] = (_Float16)fmaxf(fmaf((float)v[1], sc0.y, sh0.y), 0.f);
  o[2] = (_Float16)fmaxf(fmaf((float)v[2], sc0.z, sh0.z), 0.f);
  o[3] = (_Float16)fmaxf(fmaf((float)v[3], sc0.w, sh0.w), 0.f);
  o[4] = (_Float16)fmaxf(fmaf((float)v[4], sc1.x, sh1.x), 0.f);
  o[5] = (_Float16)fmaxf(fmaf((float)v[5], sc1.y, sh1.y), 0.f);
  o[6] = (_Float16)fmaxf(fmaf((float)v[6], sc1.z, sh1.z), 0.f);
  o[7] = (_Float16)fmaxf(fmaf((float)v[7], sc1.w, sh1.w), 0.f);
  *reinterpret_cast<f16x8*>(hn + idx * 8) = o;
}

// ---------------- 3-phase parallel pooling ----------------
__global__ void pool_init(float* __restrict__ ssum, unsigned int* __restrict__ smaxU) {
  int i = blockIdx.x * 256 + threadIdx.x;  // 32768
  ssum[i] = 0.f;
  smaxU[i] = 0x007FFFFFu;  // enc(-inf)
}

__global__ void pool_partial(const _Float16* __restrict__ z2, const float* __restrict__ scsh,
                             const int* __restrict__ batch,
                             float* __restrict__ ssum, unsigned int* __restrict__ smaxU) {
  const int c = threadIdx.x;  // 128
  const int row0 = blockIdx.x * POOL_ROWS;
  const int rowEnd = min(row0 + POOL_ROWS, NN);
  const float sc = scsh[c];
  const float sh = scsh[128 + c];

  int curb = batch[row0];
  float s = 0.f, m = -INFINITY;
  for (int row = row0; row < rowEnd; ++row) {
    int b = batch[row];
    if (b != curb) {
      atomicAdd(&ssum[curb * HD + c], s);
      atomicMax(&smaxU[curb * HD + c], encf(m));
      s = 0.f; m = -INFINITY; curb = b;
    }
    float v = fmaf((float)z2[(long)row * HD + c], sc, sh);
    s += v;
    m = fmaxf(m, v);
  }
  atomicAdd(&ssum[curb * HD + c], s);
  atomicMax(&smaxU[curb * HD + c], encf(m));
}

// ---------------- fused pool-final + gpart: gpart[b] = graph[b] @ sW1[0:384] + sb1 ----------------
__global__ void pool_gpart(const int* __restrict__ batch, const float* __restrict__ ssum,
                           const unsigned int* __restrict__ smaxU, const float* __restrict__ sW1,
                           const float* __restrict__ sb1, float* __restrict__ gpart) {
  __shared__ float sm[128], sx[128], ss[128];
  const int b = blockIdx.x;   // 256
  const int c = threadIdx.x;  // 128
  int lo = 0, hi = NN;
  while (lo < hi) { int mid = (lo + hi) >> 1; if (batch[mid] < b) lo = mid + 1; else hi = mid; }
  const int start = lo;
  hi = NN;
  while (lo < hi) { int mid = (lo + hi) >> 1; if (batch[mid] < b + 1) lo = mid + 1; else hi = mid; }
  const int cnt = lo - start;
  float s = ssum[b * HD + c];
  sm[c] = s / fmaxf((float)cnt, 1.f);
  sx[c] = (cnt > 0) ? decf(smaxU[b * HD + c]) : 0.f;
  ss[c] = s;
  __syncthreads();
  float acc = sb1[c];
  for (int k = 0; k < 128; ++k) acc = fmaf(sm[k], sW1[k * 128 + c], acc);
  for (int k = 0; k < 128; ++k) acc = fmaf(sx[k], sW1[(128 + k) * 128 + c], acc);
  for (int k = 0; k < 128; ++k) acc = fmaf(ss[k], sW1[(256 + k) * 128 + c], acc);
  gpart[b * HD + c] = acc;
}

// ---------------- head MFMA: per-order chain, one block per graph ----------------
__global__ void __launch_bounds__(128)
head_mfma(const float* __restrict__ orders, const _Float16* __restrict__ Wh,
          const float* __restrict__ ob1, const float* __restrict__ ob2,
          const float* __restrict__ gpart, const float* __restrict__ sb2,
          const float* __restrict__ sW3, const float* __restrict__ sb3,
          float* __restrict__ out) {
  __shared__ _Float16 B1[32 * 136];
  __shared__ _Float16 B2[32 * 136];
  const int t = threadIdx.x;
  const int g = blockIdx.x;
  const int row0 = g * 32;
  const int lane = t & 63;
  const int w = t >> 6;
  const int l15 = lane & 15;
  const int kgrp = lane >> 4;
  const _Float16* oW1p  = Wh;
  const _Float16* oW2p  = Wh + 4096;
  const _Float16* sW1bp = Wh + 20480;
  const _Float16* sW2p  = Wh + 36864;

  for (int idx = t; idx < 32 * 8; idx += 128) {
    int r = idx >> 3;
    int c4 = (idx & 7) * 4;
    float4 v = *reinterpret_cast<const float4*>(orders + (long)(row0 + r) * 32 + c4);
    f16x4 h;
    h[0] = (_Float16)v.x; h[1] = (_Float16)v.y; h[2] = (_Float16)v.z; h[3] = (_Float16)v.w;
    *reinterpret_cast<f16x4*>(&B1[r * 136 + c4]) = h;
  }
  __syncthreads();

  f32x4 acc[8];
  {
    f16x8 a0 = *reinterpret_cast<const f16x8*>(&B1[(w * 16 + l15) * 136 + kgrp * 8]);
#pragma unroll
    for (int tt = 0; tt < 8; ++tt) {
      float bb = ob1[tt * 16 + l15];
      acc[tt] = (f32x4){bb, bb, bb, bb};
      f16x8 bf = *reinterpret_cast<const f16x8*>(oW1p + (tt * 64 + lane) * 8);
      acc[tt] = __builtin_amdgcn_mfma_f32_16x16x32_f16(a0, bf, acc[tt], 0, 0, 0);
    }
#pragma unroll
    for (int tt = 0; tt < 8; ++tt)
#pragma unroll
      for (int j = 0; j < 4; ++j)
        B2[(w * 16 + kgrp * 4 + j) * 136 + tt * 16 + l15] = (_Float16)fmaxf(acc[tt][j], 0.f);
  }
  {
    f16x8 af[4];
#pragma unroll
    for (int s = 0; s < 4; ++s)
      af[s] = *reinterpret_cast<const f16x8*>(&B2[(w * 16 + l15) * 136 + s * 32 + kgrp * 8]);
#pragma unroll
    for (int tt = 0; tt < 8; ++tt) {
      float bb = ob2[tt * 16 + l15];
      acc[tt] = (f32x4){bb, bb, bb, bb};
#pragma unroll
      for (int s = 0; s < 4; ++s) {
        f16x8 bf = *reinterpret_cast<const f16x8*>(oW2p + ((tt * 4 + s) * 64 + lane) * 8);
        acc[tt] = __builtin_amdgcn_mfma_f32_16x16x32_f16(af[s], bf, acc[tt], 0, 0, 0);
      }
    }
#pragma unroll
    for (int tt = 0; tt < 8; ++tt)
#pragma unroll
      for (int j = 0; j < 4; ++j)
        B1[(w * 16 + kgrp * 4 + j) * 136 + tt * 16 + l15] = (_Float16)acc[tt][j];
  }
  {
    f16x8 af[4];
#pragma unroll
    for (int s = 0; s < 4; ++s)
      af[s] = *reinterpret_cast<const f16x8*>(&B1[(w * 16 + l15) * 136 + s * 32 + kgrp * 8]);
#pragma unroll
    for (int tt = 0; tt < 8; ++tt) {
      acc[tt] = (f32x4){0.f, 0.f, 0.f, 0.f};
#pragma unroll
      for (int s = 0; s < 4; ++s) {
        f16x8 bf = *reinterpret_cast<const f16x8*>(sW1bp + ((tt * 4 + s) * 64 + lane) * 8);
        acc[tt] = __builtin_amdgcn_mfma_f32_16x16x32_f16(af[s], bf, acc[tt], 0, 0, 0);
      }
    }
#pragma unroll
    for (int tt = 0; tt < 8; ++tt) {
      int c = tt * 16 + l15;
      float gp = gpart[g * HD + c];
#pragma unroll
      for (int j = 0; j < 4; ++j)
        B2[(w * 16 + kgrp * 4 + j) * 136 + c] = (_Float16)fmaxf(acc[tt][j] + gp, 0.f);
    }
  }
  {
    f16x8 af[4];
#pragma unroll
    for (int s = 0; s < 4; ++s)
      af[s] = *reinterpret_cast<const f16x8*>(&B2[(w * 16 + l15) * 136 + s * 32 + kgrp * 8]);
#pragma unroll
    for (int tt = 0; tt < 4; ++tt) {
      float bb = sb2[tt * 16 + l15];
      acc[tt] = (f32x4){bb, bb, bb, bb};
#pragma unroll
      for (int s = 0; s < 4; ++s) {
        f16x8 bf = *reinterpret_cast<const f16x8*>(sW2p + ((tt * 4 + s) * 64 + lane) * 8);
        acc[tt] = __builtin_amdgcn_mfma_f32_16x16x32_f16(af[s], bf, acc[tt], 0, 0, 0);
      }
    }
    float rsum[4] = {0.f, 0.f, 0.f, 0.f};
#pragma unroll
    for (int tt = 0; tt < 4; ++tt) {
      float wv = sW3[tt * 16 + l15];
#pragma unroll
      for (int j = 0; j < 4; ++j)
        rsum[j] = fmaf(fmaxf(acc[tt][j], 0.f), wv, rsum[j]);
    }
#pragma unroll
    for (int j = 0; j < 4; ++j) {
      rsum[j] += __shfl_xor(rsum[j], 1);
      rsum[j] += __shfl_xor(rsum[j], 2);
      rsum[j] += __shfl_xor(rsum[j], 4);
      rsum[j] += __shfl_xor(rsum[j], 8);
    }
    if (l15 == 0) {
      float b3 = sb3[0];
#pragma unroll
      for (int j = 0; j < 4; ++j)
        out[row0 + w * 16 + kgrp * 4 + j] = rsum[j] + b3;
    }
  }
}

extern "C" void kernel_launch(void* const* d_in, const int* in_sizes, int n_in,
                              void* d_out, int out_size, void* d_ws, size_t ws_size,
                              hipStream_t stream) {
  const float* x      = (const float*)d_in[0];
  const int*   ei     = (const int*)d_in[1];
  const float* orders = (const float*)d_in[2];
  const int*   batch  = (const int*)d_in[3];
  const float* gW1    = (const float*)d_in[4];
  const float* gb1    = (const float*)d_in[5];
  const float* gW2    = (const float*)d_in[6];
  const float* gb2    = (const float*)d_in[7];
  const float* gamma  = (const float*)d_in[8];
  const float* beta   = (const float*)d_in[9];
  const float* oW1    = (const float*)d_in[10];
  const float* ob1    = (const float*)d_in[11];
  const float* oW2    = (const float*)d_in[12];
  const float* ob2    = (const float*)d_in[13];
  const float* sW1    = (const float*)d_in[14];
  const float* sb1    = (const float*)d_in[15];
  const float* sW2    = (const float*)d_in[16];
  const float* sb2    = (const float*)d_in[17];
  const float* sW3    = (const float*)d_in[18];
  const float* sb3    = (const float*)d_in[19];
  float* out = (float*)d_out;

  char* ws = (char*)d_ws;
  _Float16* xh    = (_Float16*)ws;                // x fp16 / hn   [NN,128]
  _Float16* bufAh = xh + NH;                      // z fp16        [NN,128]
  _Float16* bufCh = bufAh + NH;                   // z2 fp16       [NN,128]
  float* accum2 = (float*)(bufCh + NH);           // NSUB*256 sub-accumulators
  float* scsh   = accum2 + NSUB * 256;            // 256 (scale|shift)
  float* ssum   = scsh + 256;                     // 256*128
  unsigned int* smaxU = (unsigned int*)(ssum + NB * HD);  // 256*128
  float* gpart = (float*)(smaxU + NB * HD);       // 256*128
  int* rowStart = (int*)(gpart + NB * HD);        // NN
  int* rowEnd   = rowStart + NN;                  // NN
  int* col      = rowEnd + NN;                    // NBUCK*BCAP
  unsigned int* binned = (unsigned int*)(col + NBUCK * BCAP);  // NBUCK*BCAP
  int* cursor = (int*)(binned + NBUCK * BCAP);    // 256
  _Float16* Wp  = (_Float16*)(cursor + NBUCK);    // 3*2*16384 fp16 (GIN)
  _Float16* Wh  = Wp + 3 * 32768;                 // 45056 fp16 (head)

  // ---- CSR build (by dst): cursor-allocated fixed bucket regions ----
  hipMemsetAsync(cursor, 0, NBUCK * sizeof(int), stream);
  bucket_scatter<<<NCHUNK, 256, 0, stream>>>(ei, cursor, binned);
  bucket_csr<<<NBUCK, 256, 0, stream>>>(binned, cursor, rowStart, rowEnd, col);

  // ---- pack weights + convert x + zero stats, once ----
  pack_w_kernel<<<48, 256, 0, stream>>>(gW1, gW2, Wp);
  pack_head_kernel<<<22, 256, 0, stream>>>(oW1, oW2, sW1, sW2, Wh);
  f32to16_kernel<<<(int)(NH / 8 + 255) / 256, 256, 0, stream>>>(x, xh);
  hipMemsetAsync(accum2, 0, NSUB * 256 * sizeof(float), stream);

  const int BA_GRID = (int)((NN * 16 + 255) / 256);
  for (int l = 0; l < 3; ++l) {
    // z = hn + sum_neighbors hn (xh holds x for l=0, hn of previous layer otherwise)
    gather_kernel<<<GATHER_GRID, 256, 0, stream>>>(xh, rowStart, rowEnd, col, bufAh);
    fused_layer<<<FL_GRID, 128, 0, stream>>>(
        bufAh, Wp + (long)l * 32768, gb1 + l * 128, gb2 + l * 128, bufCh, accum2);
    bn_reduce<<<1, 256, 0, stream>>>(accum2, gamma + l * 128, beta + l * 128, scsh);
    if (l < 2) bn_apply<<<BA_GRID, 256, 0, stream>>>(bufCh, scsh, xh);
  }

  // ---- pooling (BN of last layer applied via scsh) + fused gpart ----
  pool_init<<<128, 256, 0, stream>>>(ssum, smaxU);
  pool_partial<<<POOL_GRID, 128, 0, stream>>>(bufCh, scsh, batch, ssum, smaxU);
  pool_gpart<<<NB, 128, 0, stream>>>(batch, ssum, smaxU, sW1, sb1, gpart);

  // ---- head: per-order MFMA chain ----
  head_mfma<<<NB, 128, 0, stream>>>(orders, Wh, ob1, ob2, gpart, sb2, sW3, sb3, out);
}

// Round 20
// 580.095 us; speedup vs baseline: 1.0274x; 1.0274x over previous
//
#include <hip/hip_runtime.h>

static constexpr int NN = 100000;   // nodes
static constexpr int NE = 1600000;  // edges
static constexpr int NB = 256;     // graphs
static constexpr int NO = 32;      // orders per graph
static constexpr int HD = 128;     // hidden dim
static constexpr long NH = (long)NN * HD;

static constexpr int BSHIFT = 9;                 // bucket = dst >> 9
static constexpr int BSIZE = 1 << BSHIFT;        // 512 nodes per bucket
static constexpr int NBUCK = 256;
static constexpr int BCAP = 10240;               // fixed bucket capacity (max count ~8650)
static constexpr int CHUNK = 16384;
static constexpr int NCHUNK = (NE + CHUNK - 1) / CHUNK;  // 98
static constexpr int NPCH = 8;                   // pool chunks per graph
static constexpr int GATHER_GRID = NN / 4;       // 25000
static constexpr int FL_ROWS = 32;               // fused_layer rows per block
static constexpr int FL_GRID = NN / FL_ROWS;     // 3125 (exact)

typedef _Float16 f16x8 __attribute__((ext_vector_type(8)));
typedef _Float16 f16x4 __attribute__((ext_vector_type(4)));
typedef _Float16 f16x2 __attribute__((ext_vector_type(2)));
typedef float f32x4 __attribute__((ext_vector_type(4)));

// ================= CSR build: cursor-allocated fixed bucket regions =================
__global__ void bucket_scatter(const int* __restrict__ ei, int* __restrict__ cursor,
                               unsigned int* __restrict__ binned) {
  __shared__ int cnt[NBUCK];
  __shared__ int runbase[NBUCK];
  const int t = threadIdx.x;  // 256
  cnt[t] = 0;
  __syncthreads();
  long start = (long)blockIdx.x * CHUNK;
  long end = min((long)NE, start + CHUNK);
  for (long e = start + t; e < end; e += 256)
    atomicAdd(&cnt[ei[NE + e] >> BSHIFT], 1);
  __syncthreads();
  int c = cnt[t];
  runbase[t] = c ? atomicAdd(&cursor[t], c) : 0;
  cnt[t] = 0;  // reuse as local run cursor
  __syncthreads();
  for (long e = start + t; e < end; e += 256) {
    int d = ei[NE + e], s = ei[e];
    int b = d >> BSHIFT;
    int pos = b * BCAP + runbase[b] + atomicAdd(&cnt[b], 1);
    binned[pos] = ((unsigned int)s << BSHIFT) | (unsigned int)(d & (BSIZE - 1));
  }
}

// per-bucket fine counting sort -> rowStart/rowEnd + col (fixed-region layout)
__global__ void bucket_csr(const unsigned int* __restrict__ binned,
                           const int* __restrict__ cursor,
                           int* __restrict__ rowStart, int* __restrict__ rowEnd,
                           int* __restrict__ col) {
  __shared__ int cnt[BSIZE];
  __shared__ int excl[BSIZE];
  __shared__ int cur[BSIZE];
  __shared__ int part[256];
  const int b = blockIdx.x;
  const int t = threadIdx.x;  // 256
  const int lo = b * BCAP;
  const int hi = lo + cursor[b];
  cnt[t] = 0; cnt[t + 256] = 0;
  __syncthreads();
  for (int i = lo + t; i < hi; i += 256)
    atomicAdd(&cnt[binned[i] & (BSIZE - 1)], 1);
  __syncthreads();
  int a0 = cnt[2 * t], a1 = cnt[2 * t + 1];
  int s = a0 + a1;
  part[t] = s;
  __syncthreads();
  for (int off = 1; off < 256; off <<= 1) {
    int u = (t >= off) ? part[t - off] : 0;
    __syncthreads();
    part[t] += u;
    __syncthreads();
  }
  int ebase = part[t] - s;
  excl[2 * t] = ebase;
  excl[2 * t + 1] = ebase + a0;
  __syncthreads();
  const int node0 = b * BSIZE;
  for (int i = t; i < BSIZE; i += 256) {
    int node = node0 + i;
    if (node < NN) {
      rowStart[node] = lo + excl[i];
      rowEnd[node]   = lo + excl[i] + cnt[i];
    }
    cur[i] = lo + excl[i];
  }
  __syncthreads();
  for (int i = lo + t; i < hi; i += 256) {
    unsigned int v = binned[i];
    int pos = atomicAdd(&cur[v & (BSIZE - 1)], 1);
    col[pos] = (int)(v >> BSHIFT);
  }
}

// per-node insertion sort of col segments -> deterministic gather order
__global__ void sort_cols(const int* __restrict__ rowStart, const int* __restrict__ rowEnd,
                          int* __restrict__ col) {
  int n = blockIdx.x * 256 + threadIdx.x;
  if (n >= NN) return;
  int lo = rowStart[n], hi = rowEnd[n];
  for (int i = lo + 1; i < hi; ++i) {
    int key = col[i];
    int j = i - 1;
    while (j >= lo && col[j] > key) { col[j + 1] = col[j]; --j; }
    col[j + 1] = key;
  }
}

// ---------------- x fp32 -> fp16, once ----------------
__global__ void f32to16_kernel(const float* __restrict__ in, _Float16* __restrict__ out) {
  long i = (long)(blockIdx.x * 256 + threadIdx.x) * 8;
  if (i >= NH) return;
  float4 a = *reinterpret_cast<const float4*>(in + i);
  float4 b = *reinterpret_cast<const float4*>(in + i + 4);
  f16x8 v;
  v[0] = (_Float16)a.x; v[1] = (_Float16)a.y; v[2] = (_Float16)a.z; v[3] = (_Float16)a.w;
  v[4] = (_Float16)b.x; v[5] = (_Float16)b.y; v[6] = (_Float16)b.z; v[7] = (_Float16)b.w;
  *reinterpret_cast<f16x8*>(out + i) = v;
}

// ---------------- weight packing: fp32 W[128][128] -> fp16 MFMA B-fragments (GIN) ----------------
__global__ void pack_w_kernel(const float* __restrict__ gW1, const float* __restrict__ gW2,
                              _Float16* __restrict__ Wp) {
  int tid = blockIdx.x * blockDim.x + threadIdx.x;  // 3*2*8*4*64 = 12288
  if (tid >= 12288) return;
  int lane = tid & 63;
  int s = (tid >> 6) & 3;
  int t = (tid >> 8) & 7;
  int which = (tid >> 11) & 1;
  int layer = tid >> 12;
  const float* W = (which ? gW2 : gW1) + (long)layer * 128 * 128;
  _Float16* dst = Wp + (long)tid * 8;
  int kbase = s * 32 + ((lane >> 4) << 3);
  int n = t * 16 + (lane & 15);
#pragma unroll
  for (int j = 0; j < 8; ++j) dst[j] = (_Float16)W[(kbase + j) * 128 + n];
}

// ---------------- head weight packing ----------------
__global__ void pack_head_kernel(const float* __restrict__ oW1, const float* __restrict__ oW2,
                                 const float* __restrict__ sW1, const float* __restrict__ sW2,
                                 _Float16* __restrict__ dst) {
  int tid = blockIdx.x * blockDim.x + threadIdx.x;  // 5632 total
  if (tid >= 5632) return;
  const float* W; int K, N, rowOff;
  int base = tid;
  if (tid < 512)       { W = oW1; K = 32;  N = 128; rowOff = 0;   }
  else if (tid < 2560) { W = oW2; K = 128; N = 128; rowOff = 0;   base = tid - 512; }
  else if (tid < 4608) { W = sW1; K = 128; N = 128; rowOff = 384; base = tid - 2560; }
  else                 { W = sW2; K = 128; N = 64;  rowOff = 0;   base = tid - 4608; }
  int lane = base & 63;
  int fs = base >> 6;
  int NS = K >> 5;
  int s = fs % NS;
  int tt = fs / NS;
  int k = s * 32 + ((lane >> 4) << 3);
  int n = tt * 16 + (lane & 15);
  _Float16* d = dst + (long)tid * 8;
#pragma unroll
  for (int j = 0; j < 8; ++j) d[j] = (_Float16)W[(long)(rowOff + k + j) * N + n];
}

// ---------------- gather: z[n] = hn[n] + sum_j hn[col[j]]  (col sorted -> deterministic) ----------------
__global__ void gather_kernel(const _Float16* __restrict__ hin, const int* __restrict__ rowStart,
                              const int* __restrict__ rowEnd, const int* __restrict__ col,
                              _Float16* __restrict__ z) {
  const int node = (blockIdx.x * blockDim.x + threadIdx.x) >> 6;
  if (node >= NN) return;
  const int c2 = (threadIdx.x & 63) * 2;
  auto ldh = [&](int n) -> float2 {
    f16x2 h = *reinterpret_cast<const f16x2*>(hin + (long)n * HD + c2);
    return make_float2((float)h[0], (float)h[1]);
  };
  const int lo = rowStart[node];
  const int hi = rowEnd[node];
  float2 acc = ldh(node);
  int j = lo;
  for (; j + 4 <= hi; j += 4) {
    int s0 = col[j], s1 = col[j + 1], s2 = col[j + 2], s3 = col[j + 3];
    float2 v0 = ldh(s0), v1 = ldh(s1), v2 = ldh(s2), v3 = ldh(s3);
    acc.x += (v0.x + v1.x) + (v2.x + v3.x);
    acc.y += (v0.y + v1.y) + (v2.y + v3.y);
  }
  if (j < hi) {
    int last = hi - 1;
    int s0 = col[j];
    int s1 = col[min(j + 1, last)];
    int s2 = col[min(j + 2, last)];
    int s3 = col[min(j + 3, last)];
    float m1 = (j + 1 < hi) ? 1.f : 0.f;
    float m2 = (j + 2 < hi) ? 1.f : 0.f;
    float m3 = (j + 3 < hi) ? 1.f : 0.f;
    float2 v0 = ldh(s0), v1 = ldh(s1), v2 = ldh(s2), v3 = ldh(s3);
    acc.x += v0.x + m1 * v1.x + m2 * v2.x + m3 * v3.x;
    acc.y += v0.y + m1 * v1.y + m2 * v2.y + m3 * v3.y;
  }
  f16x2 o;
  o[0] = (_Float16)acc.x;
  o[1] = (_Float16)acc.y;
  *reinterpret_cast<f16x2*>(z + (long)node * HD + c2) = o;
}

// ---------------- fused GIN MLP: 128 threads / 32 rows; DETERMINISTIC stats ----------------
// Wave w owns rows [w*16, w*16+16). hidden AND z2 round-trip through the wave's own dead
// Abuf rows (DS wave-ordered, no barrier). BN stats: shfl_xor butterfly (bitwise stable)
// + fixed-order wave combine -> per-block partial[blk][256] (no atomics).
__global__ void __launch_bounds__(128)
fused_layer(const _Float16* __restrict__ Z, const _Float16* __restrict__ Wp,
            const float* __restrict__ b1, const float* __restrict__ b2,
            _Float16* __restrict__ Z2, float* __restrict__ partial) {
  __shared__ _Float16 Abuf[FL_ROWS * 136];
  __shared__ float ps[256], pq[256];  // [w*128 + c]
  const int t = threadIdx.x;
  const int row0 = blockIdx.x * FL_ROWS;
  const int lane = t & 63;
  const int w = t >> 6;            // 0..1
  const int l15 = lane & 15;
  const int kgrp = lane >> 4;

  for (int idx = t; idx < FL_ROWS * 16; idx += 128) {
    int r = idx >> 4;
    int c8 = (idx & 15) * 8;
    f16x8 v = *reinterpret_cast<const f16x8*>(Z + (long)(row0 + r) * HD + c8);
    *reinterpret_cast<f16x8*>(&Abuf[r * 136 + c8]) = v;
  }
  __syncthreads();

  f32x4 acc[8];
  // ---- GEMM1: hidden = ReLU(A @ W1 + b1) ---- (wave-local rows)
  {
    f16x8 af[4];
#pragma unroll
    for (int s = 0; s < 4; ++s)
      af[s] = *reinterpret_cast<const f16x8*>(&Abuf[(w * 16 + l15) * 136 + s * 32 + kgrp * 8]);
    const _Float16* W1p = Wp;
#pragma unroll
    for (int tt = 0; tt < 8; ++tt) {
      float bb = b1[tt * 16 + l15];
      acc[tt] = (f32x4){bb, bb, bb, bb};
#pragma unroll
      for (int s = 0; s < 4; ++s) {
        f16x8 bf = *reinterpret_cast<const f16x8*>(W1p + ((tt * 4 + s) * 64 + lane) * 8);
        acc[tt] = __builtin_amdgcn_mfma_f32_16x16x32_f16(af[s], bf, acc[tt], 0, 0, 0);
      }
    }
  }
  // hidden -> wave's own (now dead) Abuf rows; no barrier (DS wave-ordered)
#pragma unroll
  for (int tt = 0; tt < 8; ++tt) {
#pragma unroll
    for (int j = 0; j < 4; ++j) {
      float v = fmaxf(acc[tt][j], 0.f);
      Abuf[(w * 16 + kgrp * 4 + j) * 136 + tt * 16 + l15] = (_Float16)v;
    }
  }
  // ---- GEMM2: z2 = hidden @ W2 + b2 ----
  {
    f16x8 af[4];
#pragma unroll
    for (int s = 0; s < 4; ++s)
      af[s] = *reinterpret_cast<const f16x8*>(&Abuf[(w * 16 + l15) * 136 + s * 32 + kgrp * 8]);
    const _Float16* W2p = Wp + 16384;
#pragma unroll
    for (int tt = 0; tt < 8; ++tt) {
      float bb = b2[tt * 16 + l15];
      acc[tt] = (f32x4){bb, bb, bb, bb};
#pragma unroll
      for (int s = 0; s < 4; ++s) {
        f16x8 bf = *reinterpret_cast<const f16x8*>(W2p + ((tt * 4 + s) * 64 + lane) * 8);
        acc[tt] = __builtin_amdgcn_mfma_f32_16x16x32_f16(af[s], bf, acc[tt], 0, 0, 0);
      }
    }
  }
  // ---- epilogue: deterministic stats via shfl butterfly; z2 -> LDS -> coalesced store ----
#pragma unroll
  for (int tt = 0; tt < 8; ++tt) {
    int c = tt * 16 + l15;
    float s = 0.f, q = 0.f;
#pragma unroll
    for (int j = 0; j < 4; ++j) {
      float v = acc[tt][j];
      s += v; q += v * v;
      Abuf[(w * 16 + kgrp * 4 + j) * 136 + c] = (_Float16)v;
    }
    s += __shfl_xor(s, 16); s += __shfl_xor(s, 32);
    q += __shfl_xor(q, 16); q += __shfl_xor(q, 32);
    if (kgrp == 0) { ps[w * 128 + c] = s; pq[w * 128 + c] = q; }
  }
  // coalesced z2 store: lane reads contiguous f16x8 from the wave's rows (DS wave-ordered)
  for (int idx = lane; idx < 16 * 16; idx += 64) {
    int r = w * 16 + (idx >> 4);
    int c8 = (idx & 15) * 8;
    *reinterpret_cast<f16x8*>(Z2 + (long)(row0 + r) * HD + c8) =
        *reinterpret_cast<const f16x8*>(&Abuf[r * 136 + c8]);
  }
  __syncthreads();
  if (t < 128) {
    partial[(long)blockIdx.x * 256 + t]       = ps[t] + ps[128 + t];
    partial[(long)blockIdx.x * 256 + 128 + t] = pq[t] + pq[128 + t];
  }
}

// ---------------- deterministic tree-reduce of partial -> scsh (scale|shift) ----------------
__global__ void bn_reduce(const float* __restrict__ partial, const float* __restrict__ gamma,
                          const float* __restrict__ beta, float* __restrict__ scsh) {
  __shared__ float red[256];
  const int c = blockIdx.x;   // 128 (channel)
  const int t = threadIdx.x;  // 256: [0,128) sum-half, [128,256) sumsq-half
  const int ch = (t < 128) ? c : (128 + c);
  const int j = t & 127;
  float s = 0.f;
  for (int blk = j; blk < FL_GRID; blk += 128)
    s += partial[(long)blk * 256 + ch];
  red[t] = s;
  __syncthreads();
  for (int off = 64; off > 0; off >>= 1) {
    if ((t & 127) < off) red[t] += red[t + off];
    __syncthreads();
  }
  if (t == 0) {
    const float n = (float)NN;
    float mu = red[0] / n;
    float var = red[128] / n - mu * mu;
    float sc = rsqrtf(var + 1e-5f) * gamma[c];
    scsh[c] = sc;
    scsh[128 + c] = beta[c] - mu * sc;
  }
}

// ---------------- hn = ReLU(BN(z2)), elementwise ----------------
__global__ void bn_apply(const _Float16* __restrict__ z2, const float* __restrict__ scsh,
                         _Float16* __restrict__ hn) {
  long idx = (long)blockIdx.x * 256 + threadIdx.x;  // NN*16
  if (idx >= (long)NN * 16) return;
  int c8 = ((int)idx & 15) * 8;
  float4 sc0 = *reinterpret_cast<const float4*>(scsh + c8);
  float4 sc1 = *reinterpret_cast<const float4*>(scsh + c8 + 4);
  float4 sh0 = *reinterpret_cast<const float4*>(scsh + 128 + c8);
  float4 sh1 = *reinterpret_cast<const float4*>(scsh + 128 + c8 + 4);
  f16x8 v = *reinterpret_cast<const f16x8*>(z2 + idx * 8);
  f16x8 o;
  o[0] = (_Float16)fmaxf(fmaf((float)v[0], sc0.x, sh0.x), 0.f);
  o[1] = (_Float16)fmaxf(fmaf((float)v[1], sc0.y, sh0.y), 0.f);
  o[2] = (_Float16)fmaxf(fmaf((float)v[2], sc0.z, sh0.z), 0.f);
  o[3] = (_Float16)fmaxf(fmaf((float)v[3], sc0.w, sh0.w), 0.f);
  o[4] = (_Float16)fmaxf(fmaf((float)v[4], sc1.x, sh1.x), 0.f);
  o[5] = (_Float16)fmaxf(fmaf((float)v[5], sc1.y, sh1.y), 0.f);
  o[6] = (_Float16)fmaxf(fmaf((float)v[6], sc1.z, sh1.z), 0.f);
  o[7] = (_Float16)fmaxf(fmaf((float)v[7], sc1.w, sh1.w), 0.f);
  *reinterpret_cast<f16x8*>(hn + idx * 8) = o;
}

// ---------------- deterministic pooling: 8 fixed chunks per graph ----------------
__global__ void pool_partial(const _Float16* __restrict__ z2, const float* __restrict__ scsh,
                             const int* __restrict__ batch,
                             float* __restrict__ pps, float* __restrict__ ppm) {
  const int b = blockIdx.x >> 3;   // graph
  const int k = blockIdx.x & 7;    // chunk
  const int c = threadIdx.x;       // 128
  int lo = 0, hi = NN;
  while (lo < hi) { int mid = (lo + hi) >> 1; if (batch[mid] < b) lo = mid + 1; else hi = mid; }
  const int start = lo;
  hi = NN;
  while (lo < hi) { int mid = (lo + hi) >> 1; if (batch[mid] < b + 1) lo = mid + 1; else hi = mid; }
  const int end = lo;
  const int cnt = end - start;
  const int chunk = (cnt + NPCH - 1) >> 3;
  const int r0 = start + k * chunk;
  const int r1 = min(r0 + chunk, end);
  const float sc = scsh[c];
  const float sh = scsh[128 + c];
  float s = 0.f, m = -INFINITY;
  for (int row = r0; row < r1; ++row) {
    float v = fmaf((float)z2[(long)row * HD + c], sc, sh);
    s += v;
    m = fmaxf(m, v);
  }
  pps[(long)blockIdx.x * 128 + c] = s;
  ppm[(long)blockIdx.x * 128 + c] = m;
}

// ---------------- fused pool-final + gpart (fixed-order fold over 8 chunks) ----------------
__global__ void pool_gpart(const int* __restrict__ batch, const float* __restrict__ pps,
                           const float* __restrict__ ppm, const float* __restrict__ sW1,
                           const float* __restrict__ sb1, float* __restrict__ gpart) {
  __shared__ float sm[128], sx[128], ss[128];
  const int b = blockIdx.x;   // 256
  const int c = threadIdx.x;  // 128
  int lo = 0, hi = NN;
  while (lo < hi) { int mid = (lo + hi) >> 1; if (batch[mid] < b) lo = mid + 1; else hi = mid; }
  const int start = lo;
  hi = NN;
  while (lo < hi) { int mid = (lo + hi) >> 1; if (batch[mid] < b + 1) lo = mid + 1; else hi = mid; }
  const int cnt = lo - start;
  float s = 0.f, m = -INFINITY;
#pragma unroll
  for (int k = 0; k < NPCH; ++k) {
    s += pps[(long)(b * NPCH + k) * 128 + c];
    m = fmaxf(m, ppm[(long)(b * NPCH + k) * 128 + c]);
  }
  sm[c] = s / fmaxf((float)cnt, 1.f);
  sx[c] = (cnt > 0) ? m : 0.f;
  ss[c] = s;
  __syncthreads();
  float acc = sb1[c];
  for (int k = 0; k < 128; ++k) acc = fmaf(sm[k], sW1[k * 128 + c], acc);
  for (int k = 0; k < 128; ++k) acc = fmaf(sx[k], sW1[(128 + k) * 128 + c], acc);
  for (int k = 0; k < 128; ++k) acc = fmaf(ss[k], sW1[(256 + k) * 128 + c], acc);
  gpart[b * HD + c] = acc;
}

// ---------------- head MFMA: per-order chain, one block per graph ----------------
__global__ void __launch_bounds__(128)
head_mfma(const float* __restrict__ orders, const _Float16* __restrict__ Wh,
          const float* __restrict__ ob1, const float* __restrict__ ob2,
          const float* __restrict__ gpart, const float* __restrict__ sb2,
          const float* __restrict__ sW3, const float* __restrict__ sb3,
          float* __restrict__ out) {
  __shared__ _Float16 B1[32 * 136];
  __shared__ _Float16 B2[32 * 136];
  const int t = threadIdx.x;
  const int g = blockIdx.x;
  const int row0 = g * 32;
  const int lane = t & 63;
  const int w = t >> 6;
  const int l15 = lane & 15;
  const int kgrp = lane >> 4;
  const _Float16* oW1p  = Wh;
  const _Float16* oW2p  = Wh + 4096;
  const _Float16* sW1bp = Wh + 20480;
  const _Float16* sW2p  = Wh + 36864;

  for (int idx = t; idx < 32 * 8; idx += 128) {
    int r = idx >> 3;
    int c4 = (idx & 7) * 4;
    float4 v = *reinterpret_cast<const float4*>(orders + (long)(row0 + r) * 32 + c4);
    f16x4 h;
    h[0] = (_Float16)v.x; h[1] = (_Float16)v.y; h[2] = (_Float16)v.z; h[3] = (_Float16)v.w;
    *reinterpret_cast<f16x4*>(&B1[r * 136 + c4]) = h;
  }
  __syncthreads();

  f32x4 acc[8];
  {
    f16x8 a0 = *reinterpret_cast<const f16x8*>(&B1[(w * 16 + l15) * 136 + kgrp * 8]);
#pragma unroll
    for (int tt = 0; tt < 8; ++tt) {
      float bb = ob1[tt * 16 + l15];
      acc[tt] = (f32x4){bb, bb, bb, bb};
      f16x8 bf = *reinterpret_cast<const f16x8*>(oW1p + (tt * 64 + lane) * 8);
      acc[tt] = __builtin_amdgcn_mfma_f32_16x16x32_f16(a0, bf, acc[tt], 0, 0, 0);
    }
#pragma unroll
    for (int tt = 0; tt < 8; ++tt)
#pragma unroll
      for (int j = 0; j < 4; ++j)
        B2[(w * 16 + kgrp * 4 + j) * 136 + tt * 16 + l15] = (_Float16)fmaxf(acc[tt][j], 0.f);
  }
  {
    f16x8 af[4];
#pragma unroll
    for (int s = 0; s < 4; ++s)
      af[s] = *reinterpret_cast<const f16x8*>(&B2[(w * 16 + l15) * 136 + s * 32 + kgrp * 8]);
#pragma unroll
    for (int tt = 0; tt < 8; ++tt) {
      float bb = ob2[tt * 16 + l15];
      acc[tt] = (f32x4){bb, bb, bb, bb};
#pragma unroll
      for (int s = 0; s < 4; ++s) {
        f16x8 bf = *reinterpret_cast<const f16x8*>(oW2p + ((tt * 4 + s) * 64 + lane) * 8);
        acc[tt] = __builtin_amdgcn_mfma_f32_16x16x32_f16(af[s], bf, acc[tt], 0, 0, 0);
      }
    }
#pragma unroll
    for (int tt = 0; tt < 8; ++tt)
#pragma unroll
      for (int j = 0; j < 4; ++j)
        B1[(w * 16 + kgrp * 4 + j) * 136 + tt * 16 + l15] = (_Float16)acc[tt][j];
  }
  {
    f16x8 af[4];
#pragma unroll
    for (int s = 0; s < 4; ++s)
      af[s] = *reinterpret_cast<const f16x8*>(&B1[(w * 16 + l15) * 136 + s * 32 + kgrp * 8]);
#pragma unroll
    for (int tt = 0; tt < 8; ++tt) {
      acc[tt] = (f32x4){0.f, 0.f, 0.f, 0.f};
#pragma unroll
      for (int s = 0; s < 4; ++s) {
        f16x8 bf = *reinterpret_cast<const f16x8*>(sW1bp + ((tt * 4 + s) * 64 + lane) * 8);
        acc[tt] = __builtin_amdgcn_mfma_f32_16x16x32_f16(af[s], bf, acc[tt], 0, 0, 0);
      }
    }
#pragma unroll
    for (int tt = 0; tt < 8; ++tt) {
      int c = tt * 16 + l15;
      float gp = gpart[g * HD + c];
#pragma unroll
      for (int j = 0; j < 4; ++j)
        B2[(w * 16 + kgrp * 4 + j) * 136 + c] = (_Float16)fmaxf(acc[tt][j] + gp, 0.f);
    }
  }
  {
    f16x8 af[4];
#pragma unroll
    for (int s = 0; s < 4; ++s)
      af[s] = *reinterpret_cast<const f16x8*>(&B2[(w * 16 + l15) * 136 + s * 32 + kgrp * 8]);
#pragma unroll
    for (int tt = 0; tt < 4; ++tt) {
      float bb = sb2[tt * 16 + l15];
      acc[tt] = (f32x4){bb, bb, bb, bb};
#pragma unroll
      for (int s = 0; s < 4; ++s) {
        f16x8 bf = *reinterpret_cast<const f16x8*>(sW2p + ((tt * 4 + s) * 64 + lane) * 8);
        acc[tt] = __builtin_amdgcn_mfma_f32_16x16x32_f16(af[s], bf, acc[tt], 0, 0, 0);
      }
    }
    float rsum[4] = {0.f, 0.f, 0.f, 0.f};
#pragma unroll
    for (int tt = 0; tt < 4; ++tt) {
      float wv = sW3[tt * 16 + l15];
#pragma unroll
      for (int j = 0; j < 4; ++j)
        rsum[j] = fmaf(fmaxf(acc[tt][j], 0.f), wv, rsum[j]);
    }
#pragma unroll
    for (int j = 0; j < 4; ++j) {
      rsum[j] += __shfl_xor(rsum[j], 1);
      rsum[j] += __shfl_xor(rsum[j], 2);
      rsum[j] += __shfl_xor(rsum[j], 4);
      rsum[j] += __shfl_xor(rsum[j], 8);
    }
    if (l15 == 0) {
      float b3 = sb3[0];
#pragma unroll
      for (int j = 0; j < 4; ++j)
        out[row0 + w * 16 + kgrp * 4 + j] = rsum[j] + b3;
    }
  }
}

extern "C" void kernel_launch(void* const* d_in, const int* in_sizes, int n_in,
                              void* d_out, int out_size, void* d_ws, size_t ws_size,
                              hipStream_t stream) {
  const float* x      = (const float*)d_in[0];
  const int*   ei     = (const int*)d_in[1];
  const float* orders = (const float*)d_in[2];
  const int*   batch  = (const int*)d_in[3];
  const float* gW1    = (const float*)d_in[4];
  const float* gb1    = (const float*)d_in[5];
  const float* gW2    = (const float*)d_in[6];
  const float* gb2    = (const float*)d_in[7];
  const float* gamma  = (const float*)d_in[8];
  const float* beta   = (const float*)d_in[9];
  const float* oW1    = (const float*)d_in[10];
  const float* ob1    = (const float*)d_in[11];
  const float* oW2    = (const float*)d_in[12];
  const float* ob2    = (const float*)d_in[13];
  const float* sW1    = (const float*)d_in[14];
  const float* sb1    = (const float*)d_in[15];
  const float* sW2    = (const float*)d_in[16];
  const float* sb2    = (const float*)d_in[17];
  const float* sW3    = (const float*)d_in[18];
  const float* sb3    = (const float*)d_in[19];
  float* out = (float*)d_out;

  char* ws = (char*)d_ws;
  _Float16* xh    = (_Float16*)ws;                // x fp16 / hn   [NN,128]
  _Float16* bufAh = xh + NH;                      // z fp16        [NN,128]
  _Float16* bufCh = bufAh + NH;                   // z2 fp16       [NN,128]
  float* partial = (float*)(bufCh + NH);          // FL_GRID*256 BN partials
  float* scsh    = partial + (long)FL_GRID * 256; // 256 (scale|shift)
  float* pps     = scsh + 256;                    // 2048*128 pool sum partials
  float* ppm     = pps + NB * NPCH * 128;         // 2048*128 pool max partials
  float* gpart   = ppm + NB * NPCH * 128;         // 256*128
  int* rowStart = (int*)(gpart + NB * HD);        // NN
  int* rowEnd   = rowStart + NN;                  // NN
  int* col      = rowEnd + NN;                    // NBUCK*BCAP
  unsigned int* binned = (unsigned int*)(col + NBUCK * BCAP);  // NBUCK*BCAP
  int* cursor = (int*)(binned + NBUCK * BCAP);    // 256
  _Float16* Wp  = (_Float16*)(cursor + NBUCK);    // 3*2*16384 fp16 (GIN)
  _Float16* Wh  = Wp + 3 * 32768;                 // 45056 fp16 (head)

  // ---- CSR build (by dst) + per-node sort (deterministic gather order) ----
  hipMemsetAsync(cursor, 0, NBUCK * sizeof(int), stream);
  bucket_scatter<<<NCHUNK, 256, 0, stream>>>(ei, cursor, binned);
  bucket_csr<<<NBUCK, 256, 0, stream>>>(binned, cursor, rowStart, rowEnd, col);
  sort_cols<<<(NN + 255) / 256, 256, 0, stream>>>(rowStart, rowEnd, col);

  // ---- pack weights + convert x, once ----
  pack_w_kernel<<<48, 256, 0, stream>>>(gW1, gW2, Wp);
  pack_head_kernel<<<22, 256, 0, stream>>>(oW1, oW2, sW1, sW2, Wh);
  f32to16_kernel<<<(int)(NH / 8 + 255) / 256, 256, 0, stream>>>(x, xh);

  const int BA_GRID = (int)((NN * 16 + 255) / 256);
  for (int l = 0; l < 3; ++l) {
    gather_kernel<<<GATHER_GRID, 256, 0, stream>>>(xh, rowStart, rowEnd, col, bufAh);
    fused_layer<<<FL_GRID, 128, 0, stream>>>(
        bufAh, Wp + (long)l * 32768, gb1 + l * 128, gb2 + l * 128, bufCh, partial);
    bn_reduce<<<128, 256, 0, stream>>>(partial, gamma + l * 128, beta + l * 128, scsh);
    if (l < 2) bn_apply<<<BA_GRID, 256, 0, stream>>>(bufCh, scsh, xh);
  }

  // ---- deterministic pooling + fused gpart ----
  pool_partial<<<NB * NPCH, 128, 0, stream>>>(bufCh, scsh, batch, pps, ppm);
  pool_gpart<<<NB, 128, 0, stream>>>(batch, pps, ppm, sW1, sb1, gpart);

  // ---- head: per-order MFMA chain ----
  head_mfma<<<NB, 128, 0, stream>>>(orders, Wh, ob1, ob2, gpart, sb2, sW3, sb3, out);
}

// Round 21
// 509.323 us; speedup vs baseline: 1.1701x; 1.1390x over previous
//
#include <hip/hip_runtime.h>

static constexpr int NN = 100000;   // nodes
static constexpr int NE = 1600000;  // edges
static constexpr int NB = 256;     // graphs
static constexpr int NO = 32;      // orders per graph
static constexpr int HD = 128;     // hidden dim
static constexpr long NH = (long)NN * HD;

static constexpr int BSHIFT = 9;                 // bucket = dst >> 9
static constexpr int BSIZE = 1 << BSHIFT;        // 512 nodes per bucket
static constexpr int NBUCK = 256;
static constexpr int BCAP = 10240;               // fixed bucket capacity (max count ~8650)
static constexpr int CHUNK = 16384;
static constexpr int NCHUNK = (NE + CHUNK - 1) / CHUNK;  // 98
static constexpr int NPCH = 8;                   // pool chunks per graph
static constexpr int GATHER_GRID = NN / 4;       // 25000
static constexpr int FL_ROWS = 32;               // fused_layer rows per block
static constexpr int FL_GRID = NN / FL_ROWS;     // 3125 (exact)

typedef _Float16 f16x8 __attribute__((ext_vector_type(8)));
typedef _Float16 f16x4 __attribute__((ext_vector_type(4)));
typedef _Float16 f16x2 __attribute__((ext_vector_type(2)));
typedef float f32x4 __attribute__((ext_vector_type(4)));

// ================= CSR build: cursor-allocated fixed bucket regions =================
__global__ void bucket_scatter(const int* __restrict__ ei, int* __restrict__ cursor,
                               unsigned int* __restrict__ binned) {
  __shared__ int cnt[NBUCK];
  __shared__ int runbase[NBUCK];
  const int t = threadIdx.x;  // 256
  cnt[t] = 0;
  __syncthreads();
  long start = (long)blockIdx.x * CHUNK;
  long end = min((long)NE, start + CHUNK);
  for (long e = start + t; e < end; e += 256)
    atomicAdd(&cnt[ei[NE + e] >> BSHIFT], 1);
  __syncthreads();
  int c = cnt[t];
  runbase[t] = c ? atomicAdd(&cursor[t], c) : 0;
  cnt[t] = 0;  // reuse as local run cursor
  __syncthreads();
  for (long e = start + t; e < end; e += 256) {
    int d = ei[NE + e], s = ei[e];
    int b = d >> BSHIFT;
    int pos = b * BCAP + runbase[b] + atomicAdd(&cnt[b], 1);
    binned[pos] = ((unsigned int)s << BSHIFT) | (unsigned int)(d & (BSIZE - 1));
  }
}

// per-bucket fine counting sort -> rowStart/rowEnd + col (fixed-region layout)
__global__ void bucket_csr(const unsigned int* __restrict__ binned,
                           const int* __restrict__ cursor,
                           int* __restrict__ rowStart, int* __restrict__ rowEnd,
                           int* __restrict__ col) {
  __shared__ int cnt[BSIZE];
  __shared__ int excl[BSIZE];
  __shared__ int cur[BSIZE];
  __shared__ int part[256];
  const int b = blockIdx.x;
  const int t = threadIdx.x;  // 256
  const int lo = b * BCAP;
  const int hi = lo + cursor[b];
  cnt[t] = 0; cnt[t + 256] = 0;
  __syncthreads();
  for (int i = lo + t; i < hi; i += 256)
    atomicAdd(&cnt[binned[i] & (BSIZE - 1)], 1);
  __syncthreads();
  int a0 = cnt[2 * t], a1 = cnt[2 * t + 1];
  int s = a0 + a1;
  part[t] = s;
  __syncthreads();
  for (int off = 1; off < 256; off <<= 1) {
    int u = (t >= off) ? part[t - off] : 0;
    __syncthreads();
    part[t] += u;
    __syncthreads();
  }
  int ebase = part[t] - s;
  excl[2 * t] = ebase;
  excl[2 * t + 1] = ebase + a0;
  __syncthreads();
  const int node0 = b * BSIZE;
  for (int i = t; i < BSIZE; i += 256) {
    int node = node0 + i;
    if (node < NN) {
      rowStart[node] = lo + excl[i];
      rowEnd[node]   = lo + excl[i] + cnt[i];
    }
    cur[i] = lo + excl[i];
  }
  __syncthreads();
  for (int i = lo + t; i < hi; i += 256) {
    unsigned int v = binned[i];
    int pos = atomicAdd(&cur[v & (BSIZE - 1)], 1);
    col[pos] = (int)(v >> BSHIFT);
  }
}

// wave-parallel bitonic sort of each node's col segment -> deterministic gather order.
// one 64-lane wave per node; deg<=64 handled by shfl bitonic (21 steps); rare larger
// segments fall back to lane-0 insertion sort (Poisson(16) makes this ~impossible).
__global__ void sort_cols(const int* __restrict__ rowStart, const int* __restrict__ rowEnd,
                          int* __restrict__ col) {
  const int node = (blockIdx.x * blockDim.x + threadIdx.x) >> 6;
  if (node >= NN) return;
  const int lane = threadIdx.x & 63;
  const int lo = rowStart[node];
  const int len = rowEnd[node] - lo;
  if (len <= 1) return;
  if (len <= 64) {
    int v = (lane < len) ? col[lo + lane] : 0x7fffffff;
#pragma unroll
    for (int k = 2; k <= 64; k <<= 1) {
#pragma unroll
      for (int j = k >> 1; j > 0; j >>= 1) {
        int p = __shfl_xor(v, j);
        bool lower = (lane & j) == 0;
        bool asc = (lane & k) == 0;
        v = (lower == asc) ? min(v, p) : max(v, p);
      }
    }
    if (lane < len) col[lo + lane] = v;
  } else if (lane == 0) {
    const int hi = lo + len;
    for (int i = lo + 1; i < hi; ++i) {
      int key = col[i];
      int j = i - 1;
      while (j >= lo && col[j] > key) { col[j + 1] = col[j]; --j; }
      col[j + 1] = key;
    }
  }
}

// ---------------- x fp32 -> fp16, once ----------------
__global__ void f32to16_kernel(const float* __restrict__ in, _Float16* __restrict__ out) {
  long i = (long)(blockIdx.x * 256 + threadIdx.x) * 8;
  if (i >= NH) return;
  float4 a = *reinterpret_cast<const float4*>(in + i);
  float4 b = *reinterpret_cast<const float4*>(in + i + 4);
  f16x8 v;
  v[0] = (_Float16)a.x; v[1] = (_Float16)a.y; v[2] = (_Float16)a.z; v[3] = (_Float16)a.w;
  v[4] = (_Float16)b.x; v[5] = (_Float16)b.y; v[6] = (_Float16)b.z; v[7] = (_Float16)b.w;
  *reinterpret_cast<f16x8*>(out + i) = v;
}

// ---------------- weight packing: fp32 W[128][128] -> fp16 MFMA B-fragments (GIN) ----------------
__global__ void pack_w_kernel(const float* __restrict__ gW1, const float* __restrict__ gW2,
                              _Float16* __restrict__ Wp) {
  int tid = blockIdx.x * blockDim.x + threadIdx.x;  // 3*2*8*4*64 = 12288
  if (tid >= 12288) return;
  int lane = tid & 63;
  int s = (tid >> 6) & 3;
  int t = (tid >> 8) & 7;
  int which = (tid >> 11) & 1;
  int layer = tid >> 12;
  const float* W = (which ? gW2 : gW1) + (long)layer * 128 * 128;
  _Float16* dst = Wp + (long)tid * 8;
  int kbase = s * 32 + ((lane >> 4) << 3);
  int n = t * 16 + (lane & 15);
#pragma unroll
  for (int j = 0; j < 8; ++j) dst[j] = (_Float16)W[(kbase + j) * 128 + n];
}

// ---------------- head weight packing ----------------
__global__ void pack_head_kernel(const float* __restrict__ oW1, const float* __restrict__ oW2,
                                 const float* __restrict__ sW1, const float* __restrict__ sW2,
                                 _Float16* __restrict__ dst) {
  int tid = blockIdx.x * blockDim.x + threadIdx.x;  // 5632 total
  if (tid >= 5632) return;
  const float* W; int K, N, rowOff;
  int base = tid;
  if (tid < 512)       { W = oW1; K = 32;  N = 128; rowOff = 0;   }
  else if (tid < 2560) { W = oW2; K = 128; N = 128; rowOff = 0;   base = tid - 512; }
  else if (tid < 4608) { W = sW1; K = 128; N = 128; rowOff = 384; base = tid - 2560; }
  else                 { W = sW2; K = 128; N = 64;  rowOff = 0;   base = tid - 4608; }
  int lane = base & 63;
  int fs = base >> 6;
  int NS = K >> 5;
  int s = fs % NS;
  int tt = fs / NS;
  int k = s * 32 + ((lane >> 4) << 3);
  int n = tt * 16 + (lane & 15);
  _Float16* d = dst + (long)tid * 8;
#pragma unroll
  for (int j = 0; j < 8; ++j) d[j] = (_Float16)W[(long)(rowOff + k + j) * N + n];
}

// ---------------- gather: z[n] = hn[n] + sum_j hn[col[j]]  (col sorted -> deterministic) ----------------
__global__ void gather_kernel(const _Float16* __restrict__ hin, const int* __restrict__ rowStart,
                              const int* __restrict__ rowEnd, const int* __restrict__ col,
                              _Float16* __restrict__ z) {
  const int node = (blockIdx.x * blockDim.x + threadIdx.x) >> 6;
  if (node >= NN) return;
  const int c2 = (threadIdx.x & 63) * 2;
  auto ldh = [&](int n) -> float2 {
    f16x2 h = *reinterpret_cast<const f16x2*>(hin + (long)n * HD + c2);
    return make_float2((float)h[0], (float)h[1]);
  };
  const int lo = rowStart[node];
  const int hi = rowEnd[node];
  float2 acc = ldh(node);
  int j = lo;
  for (; j + 4 <= hi; j += 4) {
    int s0 = col[j], s1 = col[j + 1], s2 = col[j + 2], s3 = col[j + 3];
    float2 v0 = ldh(s0), v1 = ldh(s1), v2 = ldh(s2), v3 = ldh(s3);
    acc.x += (v0.x + v1.x) + (v2.x + v3.x);
    acc.y += (v0.y + v1.y) + (v2.y + v3.y);
  }
  if (j < hi) {
    int last = hi - 1;
    int s0 = col[j];
    int s1 = col[min(j + 1, last)];
    int s2 = col[min(j + 2, last)];
    int s3 = col[min(j + 3, last)];
    float m1 = (j + 1 < hi) ? 1.f : 0.f;
    float m2 = (j + 2 < hi) ? 1.f : 0.f;
    float m3 = (j + 3 < hi) ? 1.f : 0.f;
    float2 v0 = ldh(s0), v1 = ldh(s1), v2 = ldh(s2), v3 = ldh(s3);
    acc.x += v0.x + m1 * v1.x + m2 * v2.x + m3 * v3.x;
    acc.y += v0.y + m1 * v1.y + m2 * v2.y + m3 * v3.y;
  }
  f16x2 o;
  o[0] = (_Float16)acc.x;
  o[1] = (_Float16)acc.y;
  *reinterpret_cast<f16x2*>(z + (long)node * HD + c2) = o;
}

// ---------------- fused GIN MLP: 128 threads / 32 rows; DETERMINISTIC stats ----------------
__global__ void __launch_bounds__(128)
fused_layer(const _Float16* __restrict__ Z, const _Float16* __restrict__ Wp,
            const float* __restrict__ b1, const float* __restrict__ b2,
            _Float16* __restrict__ Z2, float* __restrict__ partial) {
  __shared__ _Float16 Abuf[FL_ROWS * 136];
  __shared__ float ps[256], pq[256];  // [w*128 + c]
  const int t = threadIdx.x;
  const int row0 = blockIdx.x * FL_ROWS;
  const int lane = t & 63;
  const int w = t >> 6;            // 0..1
  const int l15 = lane & 15;
  const int kgrp = lane >> 4;

  for (int idx = t; idx < FL_ROWS * 16; idx += 128) {
    int r = idx >> 4;
    int c8 = (idx & 15) * 8;
    f16x8 v = *reinterpret_cast<const f16x8*>(Z + (long)(row0 + r) * HD + c8);
    *reinterpret_cast<f16x8*>(&Abuf[r * 136 + c8]) = v;
  }
  __syncthreads();

  f32x4 acc[8];
  // ---- GEMM1: hidden = ReLU(A @ W1 + b1) ---- (wave-local rows)
  {
    f16x8 af[4];
#pragma unroll
    for (int s = 0; s < 4; ++s)
      af[s] = *reinterpret_cast<const f16x8*>(&Abuf[(w * 16 + l15) * 136 + s * 32 + kgrp * 8]);
    const _Float16* W1p = Wp;
#pragma unroll
    for (int tt = 0; tt < 8; ++tt) {
      float bb = b1[tt * 16 + l15];
      acc[tt] = (f32x4){bb, bb, bb, bb};
#pragma unroll
      for (int s = 0; s < 4; ++s) {
        f16x8 bf = *reinterpret_cast<const f16x8*>(W1p + ((tt * 4 + s) * 64 + lane) * 8);
        acc[tt] = __builtin_amdgcn_mfma_f32_16x16x32_f16(af[s], bf, acc[tt], 0, 0, 0);
      }
    }
  }
  // hidden -> wave's own (now dead) Abuf rows; no barrier (DS wave-ordered)
#pragma unroll
  for (int tt = 0; tt < 8; ++tt) {
#pragma unroll
    for (int j = 0; j < 4; ++j) {
      float v = fmaxf(acc[tt][j], 0.f);
      Abuf[(w * 16 + kgrp * 4 + j) * 136 + tt * 16 + l15] = (_Float16)v;
    }
  }
  // ---- GEMM2: z2 = hidden @ W2 + b2 ----
  {
    f16x8 af[4];
#pragma unroll
    for (int s = 0; s < 4; ++s)
      af[s] = *reinterpret_cast<const f16x8*>(&Abuf[(w * 16 + l15) * 136 + s * 32 + kgrp * 8]);
    const _Float16* W2p = Wp + 16384;
#pragma unroll
    for (int tt = 0; tt < 8; ++tt) {
      float bb = b2[tt * 16 + l15];
      acc[tt] = (f32x4){bb, bb, bb, bb};
#pragma unroll
      for (int s = 0; s < 4; ++s) {
        f16x8 bf = *reinterpret_cast<const f16x8*>(W2p + ((tt * 4 + s) * 64 + lane) * 8);
        acc[tt] = __builtin_amdgcn_mfma_f32_16x16x32_f16(af[s], bf, acc[tt], 0, 0, 0);
      }
    }
  }
  // ---- epilogue: deterministic stats via shfl butterfly; z2 -> LDS -> coalesced store ----
#pragma unroll
  for (int tt = 0; tt < 8; ++tt) {
    int c = tt * 16 + l15;
    float s = 0.f, q = 0.f;
#pragma unroll
    for (int j = 0; j < 4; ++j) {
      float v = acc[tt][j];
      s += v; q += v * v;
      Abuf[(w * 16 + kgrp * 4 + j) * 136 + c] = (_Float16)v;
    }
    s += __shfl_xor(s, 16); s += __shfl_xor(s, 32);
    q += __shfl_xor(q, 16); q += __shfl_xor(q, 32);
    if (kgrp == 0) { ps[w * 128 + c] = s; pq[w * 128 + c] = q; }
  }
  // coalesced z2 store: lane reads contiguous f16x8 from the wave's rows (DS wave-ordered)
  for (int idx = lane; idx < 16 * 16; idx += 64) {
    int r = w * 16 + (idx >> 4);
    int c8 = (idx & 15) * 8;
    *reinterpret_cast<f16x8*>(Z2 + (long)(row0 + r) * HD + c8) =
        *reinterpret_cast<const f16x8*>(&Abuf[r * 136 + c8]);
  }
  __syncthreads();
  if (t < 128) {
    partial[(long)blockIdx.x * 256 + t]       = ps[t] + ps[128 + t];
    partial[(long)blockIdx.x * 256 + 128 + t] = pq[t] + pq[128 + t];
  }
}

// ---------------- deterministic tree-reduce of partial -> scsh (scale|shift) ----------------
__global__ void bn_reduce(const float* __restrict__ partial, const float* __restrict__ gamma,
                          const float* __restrict__ beta, float* __restrict__ scsh) {
  __shared__ float red[256];
  const int c = blockIdx.x;   // 128 (channel)
  const int t = threadIdx.x;  // 256: [0,128) sum-half, [128,256) sumsq-half
  const int ch = (t < 128) ? c : (128 + c);
  const int j = t & 127;
  float s = 0.f;
  for (int blk = j; blk < FL_GRID; blk += 128)
    s += partial[(long)blk * 256 + ch];
  red[t] = s;
  __syncthreads();
  for (int off = 64; off > 0; off >>= 1) {
    if ((t & 127) < off) red[t] += red[t + off];
    __syncthreads();
  }
  if (t == 0) {
    const float n = (float)NN;
    float mu = red[0] / n;
    float var = red[128] / n - mu * mu;
    float sc = rsqrtf(var + 1e-5f) * gamma[c];
    scsh[c] = sc;
    scsh[128 + c] = beta[c] - mu * sc;
  }
}

// ---------------- hn = ReLU(BN(z2)), elementwise ----------------
__global__ void bn_apply(const _Float16* __restrict__ z2, const float* __restrict__ scsh,
                         _Float16* __restrict__ hn) {
  long idx = (long)blockIdx.x * 256 + threadIdx.x;  // NN*16
  if (idx >= (long)NN * 16) return;
  int c8 = ((int)idx & 15) * 8;
  float4 sc0 = *reinterpret_cast<const float4*>(scsh + c8);
  float4 sc1 = *reinterpret_cast<const float4*>(scsh + c8 + 4);
  float4 sh0 = *reinterpret_cast<const float4*>(scsh + 128 + c8);
  float4 sh1 = *reinterpret_cast<const float4*>(scsh + 128 + c8 + 4);
  f16x8 v = *reinterpret_cast<const f16x8*>(z2 + idx * 8);
  f16x8 o;
  o[0] = (_Float16)fmaxf(fmaf((float)v[0], sc0.x, sh0.x), 0.f);
  o[1] = (_Float16)fmaxf(fmaf((float)v[1], sc0.y, sh0.y), 0.f);
  o[2] = (_Float16)fmaxf(fmaf((float)v[2], sc0.z, sh0.z), 0.f);
  o[3] = (_Float16)fmaxf(fmaf((float)v[3], sc0.w, sh0.w), 0.f);
  o[4] = (_Float16)fmaxf(fmaf((float)v[4], sc1.x, sh1.x), 0.f);
  o[5] = (_Float16)fmaxf(fmaf((float)v[5], sc1.y, sh1.y), 0.f);
  o[6] = (_Float16)fmaxf(fmaf((float)v[6], sc1.z, sh1.z), 0.f);
  o[7] = (_Float16)fmaxf(fmaf((float)v[7], sc1.w, sh1.w), 0.f);
  *reinterpret_cast<f16x8*>(hn + idx * 8) = o;
}

// ---------------- deterministic pooling: 8 fixed chunks per graph ----------------
__global__ void pool_partial(const _Float16* __restrict__ z2, const float* __restrict__ scsh,
                             const int* __restrict__ batch,
                             float* __restrict__ pps, float* __restrict__ ppm) {
  const int b = blockIdx.x >> 3;   // graph
  const int k = blockIdx.x & 7;    // chunk
  const int c = threadIdx.x;       // 128
  int lo = 0, hi = NN;
  while (lo < hi) { int mid = (lo + hi) >> 1; if (batch[mid] < b) lo = mid + 1; else hi = mid; }
  const int start = lo;
  hi = NN;
  while (lo < hi) { int mid = (lo + hi) >> 1; if (batch[mid] < b + 1) lo = mid + 1; else hi = mid; }
  const int end = lo;
  const int cnt = end - start;
  const int chunk = (cnt + NPCH - 1) >> 3;
  const int r0 = start + k * chunk;
  const int r1 = min(r0 + chunk, end);
  const float sc = scsh[c];
  const float sh = scsh[128 + c];
  float s = 0.f, m = -INFINITY;
  for (int row = r0; row < r1; ++row) {
    float v = fmaf((float)z2[(long)row * HD + c], sc, sh);
    s += v;
    m = fmaxf(m, v);
  }
  pps[(long)blockIdx.x * 128 + c] = s;
  ppm[(long)blockIdx.x * 128 + c] = m;
}

// ---------------- fused pool-final + gpart (fixed-order fold over 8 chunks) ----------------
__global__ void pool_gpart(const int* __restrict__ batch, const float* __restrict__ pps,
                           const float* __restrict__ ppm, const float* __restrict__ sW1,
                           const float* __restrict__ sb1, float* __restrict__ gpart) {
  __shared__ float sm[128], sx[128], ss[128];
  const int b = blockIdx.x;   // 256
  const int c = threadIdx.x;  // 128
  int lo = 0, hi = NN;
  while (lo < hi) { int mid = (lo + hi) >> 1; if (batch[mid] < b) lo = mid + 1; else hi = mid; }
  const int start = lo;
  hi = NN;
  while (lo < hi) { int mid = (lo + hi) >> 1; if (batch[mid] < b + 1) lo = mid + 1; else hi = mid; }
  const int cnt = lo - start;
  float s = 0.f, m = -INFINITY;
#pragma unroll
  for (int k = 0; k < NPCH; ++k) {
    s += pps[(long)(b * NPCH + k) * 128 + c];
    m = fmaxf(m, ppm[(long)(b * NPCH + k) * 128 + c]);
  }
  sm[c] = s / fmaxf((float)cnt, 1.f);
  sx[c] = (cnt > 0) ? m : 0.f;
  ss[c] = s;
  __syncthreads();
  float acc = sb1[c];
  for (int k = 0; k < 128; ++k) acc = fmaf(sm[k], sW1[k * 128 + c], acc);
  for (int k = 0; k < 128; ++k) acc = fmaf(sx[k], sW1[(128 + k) * 128 + c], acc);
  for (int k = 0; k < 128; ++k) acc = fmaf(ss[k], sW1[(256 + k) * 128 + c], acc);
  gpart[b * HD + c] = acc;
}

// ---------------- head MFMA: per-order chain, one block per graph ----------------
__global__ void __launch_bounds__(128)
head_mfma(const float* __restrict__ orders, const _Float16* __restrict__ Wh,
          const float* __restrict__ ob1, const float* __restrict__ ob2,
          const float* __restrict__ gpart, const float* __restrict__ sb2,
          const float* __restrict__ sW3, const float* __restrict__ sb3,
          float* __restrict__ out) {
  __shared__ _Float16 B1[32 * 136];
  __shared__ _Float16 B2[32 * 136];
  const int t = threadIdx.x;
  const int g = blockIdx.x;
  const int row0 = g * 32;
  const int lane = t & 63;
  const int w = t >> 6;
  const int l15 = lane & 15;
  const int kgrp = lane >> 4;
  const _Float16* oW1p  = Wh;
  const _Float16* oW2p  = Wh + 4096;
  const _Float16* sW1bp = Wh + 20480;
  const _Float16* sW2p  = Wh + 36864;

  for (int idx = t; idx < 32 * 8; idx += 128) {
    int r = idx >> 3;
    int c4 = (idx & 7) * 4;
    float4 v = *reinterpret_cast<const float4*>(orders + (long)(row0 + r) * 32 + c4);
    f16x4 h;
    h[0] = (_Float16)v.x; h[1] = (_Float16)v.y; h[2] = (_Float16)v.z; h[3] = (_Float16)v.w;
    *reinterpret_cast<f16x4*>(&B1[r * 136 + c4]) = h;
  }
  __syncthreads();

  f32x4 acc[8];
  {
    f16x8 a0 = *reinterpret_cast<const f16x8*>(&B1[(w * 16 + l15) * 136 + kgrp * 8]);
#pragma unroll
    for (int tt = 0; tt < 8; ++tt) {
      float bb = ob1[tt * 16 + l15];
      acc[tt] = (f32x4){bb, bb, bb, bb};
      f16x8 bf = *reinterpret_cast<const f16x8*>(oW1p + (tt * 64 + lane) * 8);
      acc[tt] = __builtin_amdgcn_mfma_f32_16x16x32_f16(a0, bf, acc[tt], 0, 0, 0);
    }
#pragma unroll
    for (int tt = 0; tt < 8; ++tt)
#pragma unroll
      for (int j = 0; j < 4; ++j)
        B2[(w * 16 + kgrp * 4 + j) * 136 + tt * 16 + l15] = (_Float16)fmaxf(acc[tt][j], 0.f);
  }
  {
    f16x8 af[4];
#pragma unroll
    for (int s = 0; s < 4; ++s)
      af[s] = *reinterpret_cast<const f16x8*>(&B2[(w * 16 + l15) * 136 + s * 32 + kgrp * 8]);
#pragma unroll
    for (int tt = 0; tt < 8; ++tt) {
      float bb = ob2[tt * 16 + l15];
      acc[tt] = (f32x4){bb, bb, bb, bb};
#pragma unroll
      for (int s = 0; s < 4; ++s) {
        f16x8 bf = *reinterpret_cast<const f16x8*>(oW2p + ((tt * 4 + s) * 64 + lane) * 8);
        acc[tt] = __builtin_amdgcn_mfma_f32_16x16x32_f16(af[s], bf, acc[tt], 0, 0, 0);
      }
    }
#pragma unroll
    for (int tt = 0; tt < 8; ++tt)
#pragma unroll
      for (int j = 0; j < 4; ++j)
        B1[(w * 16 + kgrp * 4 + j) * 136 + tt * 16 + l15] = (_Float16)acc[tt][j];
  }
  {
    f16x8 af[4];
#pragma unroll
    for (int s = 0; s < 4; ++s)
      af[s] = *reinterpret_cast<const f16x8*>(&B1[(w * 16 + l15) * 136 + s * 32 + kgrp * 8]);
#pragma unroll
    for (int tt = 0; tt < 8; ++tt) {
      acc[tt] = (f32x4){0.f, 0.f, 0.f, 0.f};
#pragma unroll
      for (int s = 0; s < 4; ++s) {
        f16x8 bf = *reinterpret_cast<const f16x8*>(sW1bp + ((tt * 4 + s) * 64 + lane) * 8);
        acc[tt] = __builtin_amdgcn_mfma_f32_16x16x32_f16(af[s], bf, acc[tt], 0, 0, 0);
      }
    }
#pragma unroll
    for (int tt = 0; tt < 8; ++tt) {
      int c = tt * 16 + l15;
      float gp = gpart[g * HD + c];
#pragma unroll
      for (int j = 0; j < 4; ++j)
        B2[(w * 16 + kgrp * 4 + j) * 136 + c] = (_Float16)fmaxf(acc[tt][j] + gp, 0.f);
    }
  }
  {
    f16x8 af[4];
#pragma unroll
    for (int s = 0; s < 4; ++s)
      af[s] = *reinterpret_cast<const f16x8*>(&B2[(w * 16 + l15) * 136 + s * 32 + kgrp * 8]);
#pragma unroll
    for (int tt = 0; tt < 4; ++tt) {
      float bb = sb2[tt * 16 + l15];
      acc[tt] = (f32x4){bb, bb, bb, bb};
#pragma unroll
      for (int s = 0; s < 4; ++s) {
        f16x8 bf = *reinterpret_cast<const f16x8*>(sW2p + ((tt * 4 + s) * 64 + lane) * 8);
        acc[tt] = __builtin_amdgcn_mfma_f32_16x16x32_f16(af[s], bf, acc[tt], 0, 0, 0);
      }
    }
    float rsum[4] = {0.f, 0.f, 0.f, 0.f};
#pragma unroll
    for (int tt = 0; tt < 4; ++tt) {
      float wv = sW3[tt * 16 + l15];
#pragma unroll
      for (int j = 0; j < 4; ++j)
        rsum[j] = fmaf(fmaxf(acc[tt][j], 0.f), wv, rsum[j]);
    }
#pragma unroll
    for (int j = 0; j < 4; ++j) {
      rsum[j] += __shfl_xor(rsum[j], 1);
      rsum[j] += __shfl_xor(rsum[j], 2);
      rsum[j] += __shfl_xor(rsum[j], 4);
      rsum[j] += __shfl_xor(rsum[j], 8);
    }
    if (l15 == 0) {
      float b3 = sb3[0];
#pragma unroll
      for (int j = 0; j < 4; ++j)
        out[row0 + w * 16 + kgrp * 4 + j] = rsum[j] + b3;
    }
  }
}

extern "C" void kernel_launch(void* const* d_in, const int* in_sizes, int n_in,
                              void* d_out, int out_size, void* d_ws, size_t ws_size,
                              hipStream_t stream) {
  const float* x      = (const float*)d_in[0];
  const int*   ei     = (const int*)d_in[1];
  const float* orders = (const float*)d_in[2];
  const int*   batch  = (const int*)d_in[3];
  const float* gW1    = (const float*)d_in[4];
  const float* gb1    = (const float*)d_in[5];
  const float* gW2    = (const float*)d_in[6];
  const float* gb2    = (const float*)d_in[7];
  const float* gamma  = (const float*)d_in[8];
  const float* beta   = (const float*)d_in[9];
  const float* oW1    = (const float*)d_in[10];
  const float* ob1    = (const float*)d_in[11];
  const float* oW2    = (const float*)d_in[12];
  const float* ob2    = (const float*)d_in[13];
  const float* sW1    = (const float*)d_in[14];
  const float* sb1    = (const float*)d_in[15];
  const float* sW2    = (const float*)d_in[16];
  const float* sb2    = (const float*)d_in[17];
  const float* sW3    = (const float*)d_in[18];
  const float* sb3    = (const float*)d_in[19];
  float* out = (float*)d_out;

  char* ws = (char*)d_ws;
  _Float16* xh    = (_Float16*)ws;                // x fp16 / hn   [NN,128]
  _Float16* bufAh = xh + NH;                      // z fp16        [NN,128]
  _Float16* bufCh = bufAh + NH;                   // z2 fp16       [NN,128]
  float* partial = (float*)(bufCh + NH);          // FL_GRID*256 BN partials
  float* scsh    = partial + (long)FL_GRID * 256; // 256 (scale|shift)
  float* pps     = scsh + 256;                    // 2048*128 pool sum partials
  float* ppm     = pps + NB * NPCH * 128;         // 2048*128 pool max partials
  float* gpart   = ppm + NB * NPCH * 128;         // 256*128
  int* rowStart = (int*)(gpart + NB * HD);        // NN
  int* rowEnd   = rowStart + NN;                  // NN
  int* col      = rowEnd + NN;                    // NBUCK*BCAP
  unsigned int* binned = (unsigned int*)(col + NBUCK * BCAP);  // NBUCK*BCAP
  int* cursor = (int*)(binned + NBUCK * BCAP);    // 256
  _Float16* Wp  = (_Float16*)(cursor + NBUCK);    // 3*2*16384 fp16 (GIN)
  _Float16* Wh  = Wp + 3 * 32768;                 // 45056 fp16 (head)

  // ---- CSR build (by dst) + wave-parallel per-node sort (deterministic gather order) ----
  hipMemsetAsync(cursor, 0, NBUCK * sizeof(int), stream);
  bucket_scatter<<<NCHUNK, 256, 0, stream>>>(ei, cursor, binned);
  bucket_csr<<<NBUCK, 256, 0, stream>>>(binned, cursor, rowStart, rowEnd, col);
  sort_cols<<<GATHER_GRID, 256, 0, stream>>>(rowStart, rowEnd, col);

  // ---- pack weights + convert x, once ----
  pack_w_kernel<<<48, 256, 0, stream>>>(gW1, gW2, Wp);
  pack_head_kernel<<<22, 256, 0, stream>>>(oW1, oW2, sW1, sW2, Wh);
  f32to16_kernel<<<(int)(NH / 8 + 255) / 256, 256, 0, stream>>>(x, xh);

  const int BA_GRID = (int)((NN * 16 + 255) / 256);
  for (int l = 0; l < 3; ++l) {
    gather_kernel<<<GATHER_GRID, 256, 0, stream>>>(xh, rowStart, rowEnd, col, bufAh);
    fused_layer<<<FL_GRID, 128, 0, stream>>>(
        bufAh, Wp + (long)l * 32768, gb1 + l * 128, gb2 + l * 128, bufCh, partial);
    bn_reduce<<<128, 256, 0, stream>>>(partial, gamma + l * 128, beta + l * 128, scsh);
    if (l < 2) bn_apply<<<BA_GRID, 256, 0, stream>>>(bufCh, scsh, xh);
  }

  // ---- deterministic pooling + fused gpart ----
  pool_partial<<<NB * NPCH, 128, 0, stream>>>(bufCh, scsh, batch, pps, ppm);
  pool_gpart<<<NB, 128, 0, stream>>>(batch, pps, ppm, sW1, sb1, gpart);

  // ---- head: per-order MFMA chain ----
  head_mfma<<<NB, 128, 0, stream>>>(orders, Wh, ob1, ob2, gpart, sb2, sW3, sb3, out);
}